// Round 18
// baseline (334.342 us; speedup 1.0000x reference)
//
#include <hip/hip_runtime.h>

// LSTMNet: SEQ=600, B=4096, IN=6, H=30, OUT=61, fp32 in/out.
// M8 = M6 + paired h-exchange + early pairwise select.
// One wave = 2 elems (8-copy cols), 2048 waves = 2 waves/SIMD.
//   h-exchange: ds_swizzle(xor16) + 1 cvtpk builds the (even,odd) unit-pair
//   P on g-even lanes; 4 ds_bpermute fetch Bh dwords directly (was 8 bperm
//   + 4 cvtpk).  Wiring: dword d of lane (g,n) = P from lane
//   {4g+e, 32+4g+e, 4g+2+e, 32+4g+2+e}[d]; g==3 dword3 -> (0,1.0) bias slot.
//   Select: s_i computed right after C_{2i+1} -> live C quads 8 -> ~3
//   (cuts AGPR->VGPR readback pressure; VGPR=68 strangled the schedule).
//   Everything else identical to M6 (verified absmax 1.95e-3): gate-
//   interleaved A rows, own-quad = C[j] via cndmask tree, x-projection as
//   8 off-chain MFMAs with x regs 1 iter ahead / loads 2 iters ahead.

#define SEQ    600
#define BATCH  4096
#define INP    6
#define HID    30
#define NOUT   61
#define LOG2E  1.4426950408889634f
#define LOG2E2 2.8853900817779268f

typedef __fp16 f16;
typedef f16  f16x2 __attribute__((ext_vector_type(2)));
typedef f16  f16x8 __attribute__((ext_vector_type(8)));
typedef float f32x2 __attribute__((ext_vector_type(2)));
typedef float f32x4 __attribute__((ext_vector_type(4)));

__device__ __forceinline__ float rcp_(float x)  { return __builtin_amdgcn_rcpf(x); }
__device__ __forceinline__ float exp2_(float x) { return __builtin_amdgcn_exp2f(x); }
__device__ __forceinline__ unsigned cvtpk(float a, float b) {
    union { f16x2 h; unsigned u; } c;
    c.h = __builtin_amdgcn_cvt_pkrtz(a, b);
    return c.u;
}
__device__ __forceinline__ f16x8 mk8(unsigned a, unsigned b, unsigned c, unsigned d) {
    union { unsigned u[4]; f16x8 v; } x;
    x.u[0] = a; x.u[1] = b; x.u[2] = c; x.u[3] = d;
    return x.v;
}
__device__ __forceinline__ float asf(int u) {
    union { int i; float f; } c; c.i = u; return c.f;
}
__device__ __forceinline__ int asi(float f) {
    union { float f; int i; } c; c.f = f; return c.i;
}
__device__ __forceinline__ float sigm_(float x) {
    return rcp_(1.0f + exp2_(-LOG2E * x));
}
__device__ __forceinline__ float tanh_(float x) {
    return fmaf(-2.0f, rcp_(exp2_(LOG2E2 * x) + 1.0f), 1.0f);
}

extern "C" __global__ void __launch_bounds__(64, 2)
lstm_m8(const float* __restrict__ X,   const float* __restrict__ Wih,
        const float* __restrict__ Whh, const float* __restrict__ bih,
        const float* __restrict__ bhh, const float* __restrict__ W1,
        const float* __restrict__ b1,  const float* __restrict__ W2,
        const float* __restrict__ b2,  float* __restrict__ out)
{
    __shared__ float h32[2][32];   // final h per elem (epilogue only)
    __shared__ float o1s[2][32];   // fc1 activations

    const int l  = threadIdx.x;     // 0..63
    const int g  = l >> 4;          // k-group (A/B row-group)
    const int n  = l & 15;          // col
    const int e  = n & 1;           // this lane's elem slot (0/1)
    const int j  = n >> 1;          // copy index 0..7 -> this lane's tile
    const int e0 = blockIdx.x * 2;  // first elem of this wave
    const bool jb0 = (j & 1) != 0;
    const bool jb1 = (j & 2) != 0;
    const bool jb2 = (j & 4) != 0;
    const bool isg3 = (g == 3);

    // ---- pack A fragments (gate-interleaved rows; M6-verified) ----
    f16x8 Ah[8], Ax[8];
    {
        const int q = n & 3;               // gate of this lane's A rows
        #pragma unroll
        for (int m = 0; m < 8; ++m) {
            const int u  = 4 * m + (n >> 2);
            const bool ov = (u < HID);
            const int row = q * HID + (ov ? u : 0);
            unsigned dh[4], dx[4];
            #pragma unroll
            for (int jp = 0; jp < 4; ++jp) {
                const int k0 = 8 * g + 2 * jp, k1 = k0 + 1;
                float v0 = (ov && k0 < HID) ? Whh[row * HID + k0] : 0.f;
                float v1 = (ov && k1 < HID) ? Whh[row * HID + k1]
                         : ((ov && k1 == 31) ? (bih[row] + bhh[row]) : 0.f);
                dh[jp] = cvtpk(v0, v1);
                float w0 = (ov && k0 < INP) ? Wih[row * INP + k0] : 0.f;
                float w1 = (ov && k1 < INP) ? Wih[row * INP + k1] : 0.f;
                dx[jp] = cvtpk(w0, w1);
            }
            Ah[m] = mk8(dh[0], dh[1], dh[2], dh[3]);
            Ax[m] = mk8(dx[0], dx[1], dx[2], dx[3]);
        }
    }

    // ---- bperm byte addrs for the PAIRED exchange:
    //      dword d of lane (g,n) = P of lane {4g+e, 32+4g+e, 4g+2+e, 32+4g+2+e}[d]
    const int B0 = (4 * g + e) * 4;
    const int B1 = (32 + 4 * g + e) * 4;
    const int B2 = (4 * g + 2 + e) * 4;
    const int B3 = (32 + 4 * g + 2 + e) * 4;

    const float* xsrc = X + (size_t)(e0 + e) * INP;

    float c = 0.f, h = 0.f;            // cell/hidden of unit 4j+g, elem e

    f32x2 xq0, xq1, xq2;
    { const float* p = xsrc; xq0 = *(const f32x2*)p; xq1 = *(const f32x2*)(p+2); xq2 = *(const f32x2*)(p+4); }

    f32x4 xcA[8], xcB[8];
    const f32x4 ZZ = {0.f, 0.f, 0.f, 0.f};

    #define XACC(DST) do {                                                     \
        const unsigned c0 = cvtpk(xq0.x, xq0.y);                               \
        const unsigned c1 = cvtpk(xq1.x, xq1.y);                               \
        const unsigned c2 = cvtpk(xq2.x, xq2.y);                               \
        const f16x8 Bx = mk8(g == 0 ? c0 : 0u, g == 0 ? c1 : 0u,               \
                             g == 0 ? c2 : 0u, 0u);                            \
        _Pragma("unroll")                                                      \
        for (int m = 0; m < 8; ++m)                                            \
            DST[m] = __builtin_amdgcn_mfma_f32_16x16x32_f16(Ax[m], Bx, ZZ, 0, 0, 0); \
    } while (0)

    XACC(xcA);                                   // x-projection for t = 0
    { const float* p = xsrc + (size_t)BATCH * INP;   // x(1)
      xq0 = *(const f32x2*)p; xq1 = *(const f32x2*)(p+2); xq2 = *(const f32x2*)(p+4); }

    #define ITER(XC, XN, T) do {                                               \
        /* paired h-exchange: swizzle(xor16) + cvtpk + 4 bperm */              \
        const int hx_ = __builtin_amdgcn_ds_swizzle(asi(h), 0x401F);           \
        const unsigned P = cvtpk(h, asf(hx_));   /* valid on g even */         \
        const int q0 = __builtin_amdgcn_ds_bpermute(B0, (int)P);               \
        const int q1 = __builtin_amdgcn_ds_bpermute(B1, (int)P);               \
        const int q2 = __builtin_amdgcn_ds_bpermute(B2, (int)P);               \
        const int q3 = __builtin_amdgcn_ds_bpermute(B3, (int)P);               \
        const unsigned dw3 = isg3 ? 0x3C000000u : (unsigned)q3;                \
        const f16x8 Bh = mk8((unsigned)q0, (unsigned)q1, (unsigned)q2, dw3);   \
        /* 8 h-MFMAs with early pairwise select (live C quads 8 -> ~3) */      \
        f32x4 C0 = __builtin_amdgcn_mfma_f32_16x16x32_f16(Ah[0], Bh, XC[0], 0, 0, 0); \
        f32x4 C1 = __builtin_amdgcn_mfma_f32_16x16x32_f16(Ah[1], Bh, XC[1], 0, 0, 0); \
        const f32x4 s0 = jb0 ? C1 : C0;                                        \
        f32x4 C2 = __builtin_amdgcn_mfma_f32_16x16x32_f16(Ah[2], Bh, XC[2], 0, 0, 0); \
        f32x4 C3 = __builtin_amdgcn_mfma_f32_16x16x32_f16(Ah[3], Bh, XC[3], 0, 0, 0); \
        const f32x4 s1 = jb0 ? C3 : C2;                                        \
        const f32x4 t0 = jb1 ? s1 : s0;                                        \
        f32x4 C4 = __builtin_amdgcn_mfma_f32_16x16x32_f16(Ah[4], Bh, XC[4], 0, 0, 0); \
        f32x4 C5 = __builtin_amdgcn_mfma_f32_16x16x32_f16(Ah[5], Bh, XC[5], 0, 0, 0); \
        const f32x4 s2 = jb0 ? C5 : C4;                                        \
        f32x4 C6 = __builtin_amdgcn_mfma_f32_16x16x32_f16(Ah[6], Bh, XC[6], 0, 0, 0); \
        f32x4 C7 = __builtin_amdgcn_mfma_f32_16x16x32_f16(Ah[7], Bh, XC[7], 0, 0, 0); \
        const f32x4 s3 = jb0 ? C7 : C6;                                        \
        const f32x4 t1 = jb1 ? s3 : s2;                                        \
        const f32x4 G  = jb2 ? t1 : t0;                                        \
        /* off-chain: x-projection for step T+1 (x regs loaded last iter) */   \
        XACC(XN);                                                              \
        /* issue x loads for step T+2 */                                       \
        { int tt = (T) + 2; if (tt > SEQ - 1) tt = SEQ - 1;                    \
          const float* p = xsrc + (size_t)tt * BATCH * INP;                    \
          xq0 = *(const f32x2*)p; xq1 = *(const f32x2*)(p+2);                  \
          xq2 = *(const f32x2*)(p+4); }                                        \
        /* nonlin: G = (i,f,g,o) of unit 4j+g, elem e */                       \
        const float si = sigm_(G.x), sf = sigm_(G.y);                          \
        const float tg = tanh_(G.z), so = sigm_(G.w);                          \
        c = fmaf(sf, c, si * tg);                                              \
        h = so * tanh_(c);                                                     \
    } while (0)

    for (int t = 0; t < SEQ; t += 2) {
        ITER(xcA, xcB, t);
        ITER(xcB, xcA, t + 1);
    }
    #undef ITER
    #undef XACC

    // ---- epilogue (M6-verified) ----
    h32[e][4 * j + g] = h;
    asm volatile("s_waitcnt lgkmcnt(0)" ::: "memory");   // single wave

    {
        const int half = l >> 5;
        const int u    = l & 31;
        if (u < HID) {
            float a1 = b1[u];
            const float* w1r = W1 + u * HID;
            #pragma unroll
            for (int k = 0; k < HID; ++k) a1 = fmaf(w1r[k], h32[half][k], a1);
            o1s[half][u] = a1;
        }
    }
    asm volatile("s_waitcnt lgkmcnt(0)" ::: "memory");

    {
        const int half = l >> 5;
        const int u    = l & 31;
        if (u < HID) {
            for (int o = u; o < NOUT; o += HID) {
                float a2 = b2[o];
                const float* w2r = W2 + o * HID;
                #pragma unroll
                for (int k = 0; k < HID; ++k) a2 = fmaf(w2r[k], o1s[half][k], a2);
                out[(size_t)(e0 + half) * NOUT + o] = a2;
            }
        }
    }
}

extern "C" void kernel_launch(void* const* d_in, const int* in_sizes, int n_in,
                              void* d_out, int out_size, void* d_ws, size_t ws_size,
                              hipStream_t stream) {
    const float* X   = (const float*)d_in[0];
    const float* Wih = (const float*)d_in[1];
    const float* Whh = (const float*)d_in[2];
    const float* bih = (const float*)d_in[3];
    const float* bhh = (const float*)d_in[4];
    const float* W1  = (const float*)d_in[5];
    const float* b1  = (const float*)d_in[6];
    const float* W2  = (const float*)d_in[7];
    const float* b2  = (const float*)d_in[8];
    float* out = (float*)d_out;

    dim3 grid(BATCH / 2);   // 2048 single-wave blocks -> 2 waves per SIMD
    dim3 block(64);
    hipLaunchKernelGGL(lstm_m8, grid, block, 0, stream,
                       X, Wih, Whh, bih, bhh, W1, b1, W2, b2, out);
}

// Round 19
// 315.545 us; speedup vs baseline: 1.0596x; 1.0596x over previous
//
#include <hip/hip_runtime.h>

// LSTMNet: SEQ=600, B=4096, IN=6, H=30, OUT=61, fp32 in/out.
// FINAL: M4 (session-best, 317 us bench, absmax 1.95e-3) re-submitted to lock
// in the best artifact. Plateau evidence: M4/M5/M6/M7/M8 + full-asm VALU
// (R13) all land 317-345 us with wildly different pipe profiles -> bound by
// per-SIMD issue of irreducible per-step work (exchange + 10 trans + glue)
// plus chain bubbles at the 2-waves/SIMD occupancy cap (batch 4096 / elems
// per wave). Further gains need hard-pinned full-asm MFMA (out of scope).
//
// M4: one wave = 4 batch elements, fully self-contained (NO barriers).
// 1024 single-wave blocks -> 1 wave/SIMD, all 1024 SIMDs active.
//   Weight matrix rows GATE-INTERLEAVED: row R = gate(R&3), unit(R>>2).
//   Per step: C[m] = Ah[m] x Bh + xacc[m]   (8 chained MFMA, m=0..7)
//             xacc'[m] = Ax[m] x Bx(x_{t+1})  (8 off-chain MFMA, x 1 iter ahead)
//   C layout (m89-verified): col=lane&15=elem, row=4*(l>>4)+reg ->
//   lane (g,b<4): C[m] = (i,f,g,o) of unit 4m+g, elem b  (gates pre-grouped!)
//   C -> nonlin: wave-private LDS scatter (16 lanes, 8xb128) + gather
//   (64 lanes, 2xb128) -> 2 units/lane => trans issue at the chip floor.
//   h -> B-frag: 4x ds_bpermute (src lane 16b+4g+d); pair-15 = (0,1.0) bias
//   slot overwritten with 0x3C000000 (R10-verified).
// Weights are MFMA A-operands -> AGPR residency is free (R10-12 evidence).

#define SEQ    600
#define BATCH  4096
#define INP    6
#define HID    30
#define NOUT   61
#define LOG2E  1.4426950408889634f
#define LOG2E2 2.8853900817779268f

typedef __fp16 f16;
typedef f16  f16x2 __attribute__((ext_vector_type(2)));
typedef f16  f16x8 __attribute__((ext_vector_type(8)));
typedef float f32x2 __attribute__((ext_vector_type(2)));
typedef float f32x4 __attribute__((ext_vector_type(4)));

__device__ __forceinline__ float rcp_(float x)  { return __builtin_amdgcn_rcpf(x); }
__device__ __forceinline__ float exp2_(float x) { return __builtin_amdgcn_exp2f(x); }
__device__ __forceinline__ unsigned cvtpk(float a, float b) {
    union { f16x2 h; unsigned u; } c;
    c.h = __builtin_amdgcn_cvt_pkrtz(a, b);
    return c.u;
}
__device__ __forceinline__ f16x8 mk8(unsigned a, unsigned b, unsigned c, unsigned d) {
    union { unsigned u[4]; f16x8 v; } x;
    x.u[0] = a; x.u[1] = b; x.u[2] = c; x.u[3] = d;
    return x.v;
}
__device__ __forceinline__ float sigm_(float x) {
    return rcp_(1.0f + exp2_(-LOG2E * x));
}
__device__ __forceinline__ float tanh_(float x) {
    return fmaf(-2.0f, rcp_(exp2_(LOG2E2 * x) + 1.0f), 1.0f);
}

extern "C" __global__ void __launch_bounds__(64, 1)
lstm_m4(const float* __restrict__ X,   const float* __restrict__ Wih,
        const float* __restrict__ Whh, const float* __restrict__ bih,
        const float* __restrict__ bhh, const float* __restrict__ W1,
        const float* __restrict__ b1,  const float* __restrict__ W2,
        const float* __restrict__ b2,  float* __restrict__ out)
{
    // [elem][unit*4+gate] f32; elem stride 136 words -> scatter is 2-way (free)
    __shared__ __align__(16) float scr[4][136];
    __shared__ float h32[4][32];
    __shared__ float o1s[4][32];

    const int l  = threadIdx.x;     // 0..63
    const int g  = l >> 4;          // MFMA k-group; nonlin ELEM
    const int b  = l & 15;          // MFMA col (elem b<4); nonlin UNIT-PAIR v
    const int e0 = blockIdx.x * 4;  // first elem of this wave

    // ---- pack A fragments (gate-interleaved rows; R10-verified frag map) ----
    f16x8 Ah[8], Ax[8];
    {
        const int q = b & 3;              // gate of this lane's rows
        #pragma unroll
        for (int m = 0; m < 8; ++m) {
            const int u  = 4 * m + (b >> 2);   // unit
            const bool ov = (u < HID);
            const int row = q * HID + (ov ? u : 0);
            unsigned dh[4], dx[4];
            #pragma unroll
            for (int jp = 0; jp < 4; ++jp) {
                const int k0 = 8 * g + 2 * jp, k1 = k0 + 1;
                float v0 = (ov && k0 < HID) ? Whh[row * HID + k0] : 0.f;
                float v1 = (ov && k1 < HID) ? Whh[row * HID + k1]
                         : ((ov && k1 == 31) ? (bih[row] + bhh[row]) : 0.f);
                dh[jp] = cvtpk(v0, v1);
                float w0 = (ov && k0 < INP) ? Wih[row * INP + k0] : 0.f;
                float w1 = (ov && k1 < INP) ? Wih[row * INP + k1] : 0.f;
                dx[jp] = cvtpk(w0, w1);
            }
            Ah[m] = mk8(dh[0], dh[1], dh[2], dh[3]);
            Ax[m] = mk8(dx[0], dx[1], dx[2], dx[3]);
        }
    }

    // bpermute addrs: Bh dword d comes from lane 16*b + 4*g + d (its P reg)
    const int ad0 = ((16 * b + 4 * g + 0) & 63) * 4;
    const int ad1 = ((16 * b + 4 * g + 1) & 63) * 4;
    const int ad2 = ((16 * b + 4 * g + 2) & 63) * 4;
    const int ad3 = ((16 * b + 4 * g + 3) & 63) * 4;
    const bool isg3 = (g == 3);

    // per-lane x source: elem b&3 (cols 4..15 duplicate col b&3 -> harmless)
    const float* xsrc = X + (size_t)(e0 + (b & 3)) * INP;

    unsigned P = 0;                    // this lane's h pair (units 2b, 2b+1), elem g
    float cA = 0.f, cB = 0.f;          // cell state for units 2b, 2b+1
    float hA = 0.f, hB = 0.f;

    f32x2 xq0, xq1, xq2;
    { const float* p = xsrc; xq0 = *(const f32x2*)p; xq1 = *(const f32x2*)(p+2); xq2 = *(const f32x2*)(p+4); }

    f32x4 xcA[8], xcB[8];
    const f32x4 ZZ = {0.f, 0.f, 0.f, 0.f};

    #define XACC(DST) do {                                                     \
        const unsigned c0 = cvtpk(xq0.x, xq0.y);                               \
        const unsigned c1 = cvtpk(xq1.x, xq1.y);                               \
        const unsigned c2 = cvtpk(xq2.x, xq2.y);                               \
        const f16x8 Bx = mk8(g == 0 ? c0 : 0u, g == 0 ? c1 : 0u,               \
                             g == 0 ? c2 : 0u, 0u);                            \
        _Pragma("unroll")                                                      \
        for (int m = 0; m < 8; ++m)                                            \
            DST[m] = __builtin_amdgcn_mfma_f32_16x16x32_f16(Ax[m], Bx, ZZ, 0, 0, 0); \
    } while (0)

    XACC(xcA);                                   // x-projection for t = 0
    { const float* p = xsrc + (size_t)BATCH * INP;   // x(1)
      xq0 = *(const f32x2*)p; xq1 = *(const f32x2*)(p+2); xq2 = *(const f32x2*)(p+4); }

    #define ITER(XC, XN, T) do {                                               \
        /* Bh from P via 4 bpermutes; pair-15 = (0, 1.0) bias slot */          \
        unsigned d0 = (unsigned)__builtin_amdgcn_ds_bpermute(ad0, (int)P);     \
        unsigned d1 = (unsigned)__builtin_amdgcn_ds_bpermute(ad1, (int)P);     \
        unsigned d2 = (unsigned)__builtin_amdgcn_ds_bpermute(ad2, (int)P);     \
        unsigned d3 = (unsigned)__builtin_amdgcn_ds_bpermute(ad3, (int)P);     \
        d3 = isg3 ? 0x3C000000u : d3;                                          \
        const f16x8 Bh = mk8(d0, d1, d2, d3);                                  \
        f32x4 C[8];                                                            \
        _Pragma("unroll")                                                      \
        for (int m = 0; m < 8; ++m)                                            \
            C[m] = __builtin_amdgcn_mfma_f32_16x16x32_f16(Ah[m], Bh, XC[m], 0, 0, 0); \
        /* off-chain: x-projection for step T+1 from x regs loaded last iter */\
        XACC(XN);                                                              \
        /* issue x loads for step T+2 */                                       \
        { int tt = (T) + 2; if (tt > SEQ - 1) tt = SEQ - 1;                    \
          const float* p = xsrc + (size_t)tt * BATCH * INP;                    \
          xq0 = *(const f32x2*)p; xq1 = *(const f32x2*)(p+2);                  \
          xq2 = *(const f32x2*)(p+4); }                                        \
        /* scatter C: 16 real-col lanes write [elem][unit][gate] */            \
        if (b < 4) {                                                           \
            _Pragma("unroll")                                                  \
            for (int m = 0; m < 8; ++m)                                        \
                *(f32x4*)&scr[b][(4 * m + g) * 4] = C[m];                      \
        }                                                                      \
        /* gather: this lane's units 2b, 2b+1 of elem g */                     \
        const f32x4 gA = *(const f32x4*)&scr[g][(2 * b) * 4];                  \
        const f32x4 gB = *(const f32x4*)&scr[g][(2 * b + 1) * 4];              \
        /* nonlin: gA/gB = (i,f,g,o) */                                        \
        const float siA = sigm_(gA.x), sfA = sigm_(gA.y);                      \
        const float tgA = tanh_(gA.z), soA = sigm_(gA.w);                      \
        const float siB = sigm_(gB.x), sfB = sigm_(gB.y);                      \
        const float tgB = tanh_(gB.z), soB = sigm_(gB.w);                      \
        cA = fmaf(sfA, cA, siA * tgA);                                         \
        cB = fmaf(sfB, cB, siB * tgB);                                         \
        hA = soA * tanh_(cA);                                                  \
        hB = soB * tanh_(cB);                                                  \
        P = cvtpk(hA, hB);                                                     \
    } while (0)

    for (int t = 0; t < SEQ; t += 2) {
        ITER(xcA, xcB, t);
        ITER(xcB, xcA, t + 1);
    }
    #undef ITER
    #undef XACC

    // ---- epilogue: lane (g, b=v) holds h of elem g, units 2v, 2v+1 ----
    if (b < 15) {
        h32[g][2 * b]     = hA;
        h32[g][2 * b + 1] = hB;
    }
    asm volatile("s_waitcnt lgkmcnt(0)" ::: "memory");   // single wave

    // FC1: lane (g, j): rows j and j+16 (j<14) of elem g
    {
        float hr[HID];
        #pragma unroll
        for (int k = 0; k < HID; ++k) hr[k] = h32[g][k];
        float a0 = b1[b];
        const float* w1r0 = W1 + b * HID;
        #pragma unroll
        for (int k = 0; k < HID; ++k) a0 = fmaf(w1r0[k], hr[k], a0);
        o1s[g][b] = a0;
        if (b < 14) {
            float a1 = b1[b + 16];
            const float* w1r1 = W1 + (b + 16) * HID;
            #pragma unroll
            for (int k = 0; k < HID; ++k) a1 = fmaf(w1r1[k], hr[k], a1);
            o1s[g][b + 16] = a1;
        }
    }
    asm volatile("s_waitcnt lgkmcnt(0)" ::: "memory");

    // FC2: lane (g, j): rows j, j+16, j+32, j+48 (<61) of elem g
    {
        float orr[HID];
        #pragma unroll
        for (int k = 0; k < HID; ++k) orr[k] = o1s[g][k];
        #pragma unroll
        for (int r = 0; r < 4; ++r) {
            const int o = b + 16 * r;
            if (o < NOUT) {
                float a2 = b2[o];
                const float* w2r = W2 + o * HID;
                #pragma unroll
                for (int k = 0; k < HID; ++k) a2 = fmaf(w2r[k], orr[k], a2);
                out[(size_t)(e0 + g) * NOUT + o] = a2;
            }
        }
    }
}

extern "C" void kernel_launch(void* const* d_in, const int* in_sizes, int n_in,
                              void* d_out, int out_size, void* d_ws, size_t ws_size,
                              hipStream_t stream) {
    const float* X   = (const float*)d_in[0];
    const float* Wih = (const float*)d_in[1];
    const float* Whh = (const float*)d_in[2];
    const float* bih = (const float*)d_in[3];
    const float* bhh = (const float*)d_in[4];
    const float* W1  = (const float*)d_in[5];
    const float* b1  = (const float*)d_in[6];
    const float* W2  = (const float*)d_in[7];
    const float* b2  = (const float*)d_in[8];
    float* out = (float*)d_out;

    dim3 grid(BATCH / 4);   // 1024 single-wave blocks -> 1 wave per SIMD
    dim3 block(64);
    hipLaunchKernelGGL(lstm_m4, grid, block, 0, stream,
                       X, Wih, Whh, bih, bhh, W1, b1, W2, b2, out);
}